// Round 2
// baseline (389.662 us; speedup 1.0000x reference)
//
#include <hip/hip_runtime.h>
#include <hip/hip_bf16.h>

#define D1 8
#define RANK 8
#define ROWS 4   // rows per thread: amortizes G-coefficient loads 4x

__global__ __launch_bounds__(256) void tt_poly_kernel(
    const float* __restrict__ X,
    const float* __restrict__ G0,   // [d1, r]
    const float* __restrict__ G1,   // [r, d1, r]
    const float* __restrict__ G2,   // [r, d1, r]
    const float* __restrict__ G3,   // [r, d1]
    float* __restrict__ out,
    int B, int S)                   // S = total threads (row stride)
{
    int gid = blockIdx.x * blockDim.x + threadIdx.x;

    // ---- load ROWS rows of X, coalesced (stride S keeps lanes contiguous) ----
    float4 x[ROWS];
    #pragma unroll
    for (int k = 0; k < ROWS; ++k) {
        int b = gid + k * S;
        x[k] = (b < B) ? reinterpret_cast<const float4*>(X)[b]
                       : make_float4(0.f, 0.f, 0.f, 0.f);
    }

    // ---- stage 1: t0[k][r] = sum_d x0^d G0[d][r], Horner; G0 row loaded once per d ----
    float t0[ROWS][RANK];
    {
        float g[RANK];
        #pragma unroll
        for (int r = 0; r < RANK; ++r) g[r] = G0[(D1 - 1) * RANK + r];
        #pragma unroll
        for (int k = 0; k < ROWS; ++k)
            #pragma unroll
            for (int r = 0; r < RANK; ++r) t0[k][r] = g[r];
        #pragma unroll
        for (int d = D1 - 2; d >= 0; --d) {
            #pragma unroll
            for (int r = 0; r < RANK; ++r) g[r] = G0[d * RANK + r];
            #pragma unroll
            for (int k = 0; k < ROWS; ++k)
                #pragma unroll
                for (int r = 0; r < RANK; ++r)
                    t0[k][r] = fmaf(t0[k][r], x[k].x, g[r]);
        }
    }

    // ---- stage 2: t1[k][s] = sum_{r,d} t0[k][r] G1[r][d][s] x1^d ----
    // per-d coefficient block (64 floats) loaded once, used ROWS*8 times
    float t1[ROWS][RANK];
    {
        #pragma unroll
        for (int k = 0; k < ROWS; ++k)
            #pragma unroll
            for (int s = 0; s < RANK; ++s) t1[k][s] = 0.f;

        #pragma unroll
        for (int dd = 0; dd < D1; ++dd) {
            const int d = D1 - 1 - dd;           // d: 7 .. 0
            float c[ROWS][RANK];
            #pragma unroll
            for (int k = 0; k < ROWS; ++k)
                #pragma unroll
                for (int s = 0; s < RANK; ++s) c[k][s] = 0.f;
            #pragma unroll
            for (int r = 0; r < RANK; ++r) {
                float g[RANK];
                #pragma unroll
                for (int s = 0; s < RANK; ++s)
                    g[s] = G1[(r * D1 + d) * RANK + s];
                #pragma unroll
                for (int k = 0; k < ROWS; ++k)
                    #pragma unroll
                    for (int s = 0; s < RANK; ++s)
                        c[k][s] = fmaf(t0[k][r], g[s], c[k][s]);
            }
            if (dd == 0) {
                #pragma unroll
                for (int k = 0; k < ROWS; ++k)
                    #pragma unroll
                    for (int s = 0; s < RANK; ++s) t1[k][s] = c[k][s];
            } else {
                #pragma unroll
                for (int k = 0; k < ROWS; ++k)
                    #pragma unroll
                    for (int s = 0; s < RANK; ++s)
                        t1[k][s] = fmaf(t1[k][s], x[k].y, c[k][s]);
            }
        }
    }

    // ---- stage 3: same with G2, x2 ----
    float t2[ROWS][RANK];
    {
        #pragma unroll
        for (int k = 0; k < ROWS; ++k)
            #pragma unroll
            for (int s = 0; s < RANK; ++s) t2[k][s] = 0.f;

        #pragma unroll
        for (int dd = 0; dd < D1; ++dd) {
            const int d = D1 - 1 - dd;
            float c[ROWS][RANK];
            #pragma unroll
            for (int k = 0; k < ROWS; ++k)
                #pragma unroll
                for (int s = 0; s < RANK; ++s) c[k][s] = 0.f;
            #pragma unroll
            for (int r = 0; r < RANK; ++r) {
                float g[RANK];
                #pragma unroll
                for (int s = 0; s < RANK; ++s)
                    g[s] = G2[(r * D1 + d) * RANK + s];
                #pragma unroll
                for (int k = 0; k < ROWS; ++k)
                    #pragma unroll
                    for (int s = 0; s < RANK; ++s)
                        c[k][s] = fmaf(t1[k][r], g[s], c[k][s]);
            }
            if (dd == 0) {
                #pragma unroll
                for (int k = 0; k < ROWS; ++k)
                    #pragma unroll
                    for (int s = 0; s < RANK; ++s) t2[k][s] = c[k][s];
            } else {
                #pragma unroll
                for (int k = 0; k < ROWS; ++k)
                    #pragma unroll
                    for (int s = 0; s < RANK; ++s)
                        t2[k][s] = fmaf(t2[k][s], x[k].z, c[k][s]);
            }
        }
    }

    // ---- stage 4: res[k] = sum_{t,d} t2[k][t] G3[t][d] x3^d, Horner over d ----
    float res[ROWS];
    #pragma unroll
    for (int k = 0; k < ROWS; ++k) res[k] = 0.f;
    #pragma unroll
    for (int dd = 0; dd < D1; ++dd) {
        const int d = D1 - 1 - dd;
        float g[RANK];
        #pragma unroll
        for (int t = 0; t < RANK; ++t) g[t] = G3[t * D1 + d];
        #pragma unroll
        for (int k = 0; k < ROWS; ++k) {
            float e = 0.f;
            #pragma unroll
            for (int t = 0; t < RANK; ++t)
                e = fmaf(t2[k][t], g[t], e);
            res[k] = fmaf(res[k], x[k].w, e);
        }
    }

    #pragma unroll
    for (int k = 0; k < ROWS; ++k) {
        int b = gid + k * S;
        if (b < B) out[b] = res[k];
    }
}

extern "C" void kernel_launch(void* const* d_in, const int* in_sizes, int n_in,
                              void* d_out, int out_size, void* d_ws, size_t ws_size,
                              hipStream_t stream) {
    const float* X  = (const float*)d_in[0];
    const float* G0 = (const float*)d_in[1];
    const float* G1 = (const float*)d_in[2];
    const float* G2 = (const float*)d_in[3];
    const float* G3 = (const float*)d_in[4];
    float* out = (float*)d_out;

    int B = in_sizes[0] / 4;   // X is [B,4]
    int block = 256;
    int grid = (B + block * ROWS - 1) / (block * ROWS);
    int S = grid * block;
    tt_poly_kernel<<<grid, block, 0, stream>>>(X, G0, G1, G2, G3, out, B, S);
}